// Round 2
// baseline (1599.183 us; speedup 1.0000x reference)
//
#include <hip/hip_runtime.h>
#include <math.h>

#define NB    2048
#define THIST 15
#define NSEG  20
#define MAXIT 48

#define cA21 ((float)0.161)
#define cA31 ((float)-0.008480655492356989)
#define cA32 ((float)0.335480655492357)
#define cA41 ((float)2.8971530571054935)
#define cA42 ((float)-6.359448489975075)
#define cA43 ((float)4.3622954328695815)
#define cA51 ((float)5.325864828439257)
#define cA52 ((float)-11.748883564062828)
#define cA53 ((float)7.4955393428898365)
#define cA54 ((float)-0.09249506636175525)
#define cA61 ((float)5.86145544294642)
#define cA62 ((float)-12.92096931784711)
#define cA63 ((float)8.159367898576159)
#define cA64 ((float)-0.071584973281401)
#define cA65 ((float)-0.028269050394068383)
#define cB1  ((float)0.09646076681806523)
#define cB2  ((float)0.01)
#define cB3  ((float)0.4798896504144996)
#define cB4  ((float)1.379008574103742)
#define cB5  ((float)-3.290069515436081)
#define cB6  ((float)2.324710524099774)
#define cE1  ((float)-0.001780011052225777)
#define cE2  ((float)-0.0008164344596567469)
#define cE3  ((float)0.007880878010261995)
#define cE4  ((float)-0.1447110071732629)
#define cE5  ((float)0.5823571654525552)
#define cE6  ((float)-0.45808210592918697)
#define cE7  ((float)0.015151515151515152)

__device__ __forceinline__ float softplus_f(float x) {
    // softplus(x) = max(x,0) + log1p(exp(-|x|)), via exp2/log2 HW ops
    float t = exp2f(-fabsf(x) * 1.442695040888963f);
    float l = log2f(1.0f + t) * 0.6931471805599453f;
    return fmaxf(x, 0.0f) + l;
}

__device__ __forceinline__ float4 softplus4(float4 a) {
    float4 r;
    r.x = softplus_f(a.x); r.y = softplus_f(a.y);
    r.z = softplus_f(a.z); r.w = softplus_f(a.w);
    return r;
}

// block = 256 threads = 4 waves = 8 elements (2 elements per wave, half-wave each)
__global__ __launch_bounds__(256, 1)
void ode_kernel(const float* __restrict__ history,
                const float* __restrict__ W1, const float* __restrict__ b1,
                const float* __restrict__ W2, const float* __restrict__ b2,
                const float* __restrict__ W3, const float* __restrict__ b3,
                float* __restrict__ out)
{
    // w1q[k*128 + j] = W1[j][k]  (j = 4*sub + j')   : lane reads float4 of 4 j's at one k
    // w2q[k*128 + j] = W2[j][k]                     : same
    // w3q[k2*128 + sub*4 + c] = W3[2*sub + (c&1)][2*k2 + (c>>1)]
    __shared__ float w1q[64 * 128];
    __shared__ float w2q[128 * 128];
    __shared__ float w3q[64 * 128];
    __shared__ float b1s[128], b2s[128], b3s[64];
    __shared__ float act[8][320];   // per element slot: arg[0:64] h1[64:192] h2[192:320]

    const int tid = threadIdx.x;

    // Staging: coalesced-consecutive LDS writes (conflict-free); global reads strided
    // (one-time, L2/L3-absorbed).
    for (int i = tid; i < 64 * 128; i += 256)
        w1q[i] = W1[(i & 127) * 64 + (i >> 7)];
    for (int i = tid; i < 128 * 128; i += 256)
        w2q[i] = W2[(i & 127) * 128 + (i >> 7)];
    for (int i = tid; i < 64 * 128; i += 256) {
        int k2 = i >> 7, r = i & 127, s = r >> 2, c = r & 3;
        w3q[i] = W3[(2 * s + (c & 1)) * 128 + 2 * k2 + (c >> 1)];
    }
    if (tid < 128) { b1s[tid] = b1[tid]; b2s[tid] = b2[tid]; }
    if (tid < 64)  { b3s[tid] = b3[tid]; }
    __syncthreads();

    const int wave = tid >> 6, lane = tid & 63;
    const int e    = lane >> 5, sub = lane & 31;
    const int slot = wave * 2 + e;
    const int elem = blockIdx.x * 8 + slot;

    // Register-cache W2 first half (k in [0,64)): 64 float4 = 256 VGPRs
    float4 wc[64];
#pragma unroll
    for (int k = 0; k < 64; ++k)
        wc[k] = *(const float4*)&w2q[k * 128 + sub * 4];

    const float4 b1f = ((const float4*)b1s)[sub];
    const float4 b2f = ((const float4*)b2s)[sub];
    const float2 b3f = ((const float2*)b3s)[sub];

    float* myact = act[slot];
    const float4* argv = (const float4*)myact;
    const float4* h1v  = (const float4*)(myact + 64);
    const float4* h2v  = (const float4*)(myact + 192);

    // One MLP eval for this half-wave's element; arg is this lane's 2 dims.
    auto mlp = [&](float2 arg) -> float2 {
        ((float2*)myact)[sub] = arg;
        __builtin_amdgcn_wave_barrier();

        // ---- L1: h1[4sub..4sub+3] ----
        float4 a = b1f;
#pragma unroll
        for (int kk = 0; kk < 16; ++kk) {
            float4 av = argv[kk];
#pragma unroll
            for (int c = 0; c < 4; ++c) {
                const float4 w = *(const float4*)&w1q[(4 * kk + c) * 128 + sub * 4];
                float s = (c == 0) ? av.x : (c == 1) ? av.y : (c == 2) ? av.z : av.w;
                a.x = fmaf(s, w.x, a.x); a.y = fmaf(s, w.y, a.y);
                a.z = fmaf(s, w.z, a.z); a.w = fmaf(s, w.w, a.w);
            }
        }
        float4 h1 = softplus4(a);
        ((float4*)(myact + 64))[sub] = h1;
        __builtin_amdgcn_wave_barrier();

        // ---- L2: h2[4sub..4sub+3] ----
        float4 b = b2f;
#pragma unroll
        for (int kk = 0; kk < 16; ++kk) {            // k in [0,64): register-cached weights
            float4 hv = h1v[kk];
#pragma unroll
            for (int c = 0; c < 4; ++c) {
                const float4 w = wc[4 * kk + c];
                float s = (c == 0) ? hv.x : (c == 1) ? hv.y : (c == 2) ? hv.z : hv.w;
                b.x = fmaf(s, w.x, b.x); b.y = fmaf(s, w.y, b.y);
                b.z = fmaf(s, w.z, b.z); b.w = fmaf(s, w.w, b.w);
            }
        }
#pragma unroll
        for (int kk = 16; kk < 32; ++kk) {           // k in [64,128): LDS weights
            float4 hv = h1v[kk];
#pragma unroll
            for (int c = 0; c < 4; ++c) {
                const float4 w = *(const float4*)&w2q[(4 * kk + c) * 128 + sub * 4];
                float s = (c == 0) ? hv.x : (c == 1) ? hv.y : (c == 2) ? hv.z : hv.w;
                b.x = fmaf(s, w.x, b.x); b.y = fmaf(s, w.y, b.y);
                b.z = fmaf(s, w.z, b.z); b.w = fmaf(s, w.w, b.w);
            }
        }
        float4 h2 = softplus4(b);
        ((float4*)(myact + 192))[sub] = h2;
        __builtin_amdgcn_wave_barrier();

        // ---- L3: out dims {2sub, 2sub+1} ----
        float2 o = b3f;
#pragma unroll
        for (int k4 = 0; k4 < 32; ++k4) {
            float4 hv = h2v[k4];
#pragma unroll
            for (int i = 0; i < 2; ++i) {
                const float4 w = *(const float4*)&w3q[(2 * k4 + i) * 128 + sub * 4];
                float s0 = (i == 0) ? hv.x : hv.z;
                float s1 = (i == 0) ? hv.y : hv.w;
                o.x = fmaf(s0, w.x, fmaf(s1, w.z, o.x));
                o.y = fmaf(s0, w.y, fmaf(s1, w.w, o.y));
            }
        }
        return o;
    };

    float2 yv = *(const float2*)&history[(size_t)elem * (THIST * 64) + 14 * 64 + 2 * sub];
    float dt = 0.1f;

#pragma unroll 1
    for (int seg = 1; seg <= NSEG; ++seg) {
        const float t1 = (float)seg;
        float t = t1 - 1.0f;
        bool done = false;

#pragma unroll 1
        for (int it = 0; it < MAXIT; ++it) {
            float dt_c = fminf(dt, t1 - t);
            float h = dt_c;

            float2 k1, k2v, k3, k4v, k5, k6, k7, y5;
            y5.x = 0.f; y5.y = 0.f;
#pragma unroll 1
            for (int st = 0; st < 7; ++st) {
                float2 s;
                switch (st) {
                    case 0: s.x = 0.f; s.y = 0.f; break;
                    case 1: s.x = cA21 * k1.x;
                            s.y = cA21 * k1.y; break;
                    case 2: s.x = fmaf(cA31, k1.x, cA32 * k2v.x);
                            s.y = fmaf(cA31, k1.y, cA32 * k2v.y); break;
                    case 3: s.x = fmaf(cA41, k1.x, fmaf(cA42, k2v.x, cA43 * k3.x));
                            s.y = fmaf(cA41, k1.y, fmaf(cA42, k2v.y, cA43 * k3.y)); break;
                    case 4: s.x = fmaf(cA51, k1.x, fmaf(cA52, k2v.x, fmaf(cA53, k3.x, cA54 * k4v.x)));
                            s.y = fmaf(cA51, k1.y, fmaf(cA52, k2v.y, fmaf(cA53, k3.y, cA54 * k4v.y))); break;
                    case 5: s.x = fmaf(cA61, k1.x, fmaf(cA62, k2v.x, fmaf(cA63, k3.x, fmaf(cA64, k4v.x, cA65 * k5.x))));
                            s.y = fmaf(cA61, k1.y, fmaf(cA62, k2v.y, fmaf(cA63, k3.y, fmaf(cA64, k4v.y, cA65 * k5.y)))); break;
                    default: s.x = fmaf(cB1, k1.x, fmaf(cB2, k2v.x, fmaf(cB3, k3.x, fmaf(cB4, k4v.x, fmaf(cB5, k5.x, cB6 * k6.x)))));
                             s.y = fmaf(cB1, k1.y, fmaf(cB2, k2v.y, fmaf(cB3, k3.y, fmaf(cB4, k4v.y, fmaf(cB5, k5.y, cB6 * k6.y))))); break;
                }
                float2 arg;
                arg.x = fmaf(h, s.x, yv.x);
                arg.y = fmaf(h, s.y, yv.y);
                if (st == 6) y5 = arg;
                float2 kv = mlp(arg);
                switch (st) {
                    case 0: k1 = kv; break;
                    case 1: k2v = kv; break;
                    case 2: k3 = kv; break;
                    case 3: k4v = kv; break;
                    case 4: k5 = kv; break;
                    case 5: k6 = kv; break;
                    default: k7 = kv; break;
                }
            }

            float2 es;
            es.x = fmaf(cE1, k1.x, fmaf(cE2, k2v.x, fmaf(cE3, k3.x,
                   fmaf(cE4, k4v.x, fmaf(cE5, k5.x, fmaf(cE6, k6.x, cE7 * k7.x))))));
            es.y = fmaf(cE1, k1.y, fmaf(cE2, k2v.y, fmaf(cE3, k3.y,
                   fmaf(cE4, k4v.y, fmaf(cE5, k5.y, fmaf(cE6, k6.y, cE7 * k7.y))))));
            float ex = h * es.x, ey = h * es.y;
            float scx = fmaf(1e-3f, fmaxf(fabsf(yv.x), fabsf(y5.x)), 1e-6f);
            float scy = fmaf(1e-3f, fmaxf(fabsf(yv.y), fabsf(y5.y)), 1e-6f);
            float rx = ex / scx, ry = ey / scy;
            float rr = fmaf(rx, rx, ry * ry);
#pragma unroll
            for (int off = 1; off <= 16; off <<= 1)
                rr += __shfl_xor(rr, off, 64);      // reduce within each 32-lane half
            float en = sqrtf(rr * (1.0f / 64.0f));

            bool accept = (en <= 1.0f) && !done;
            float fac = 0.9f * exp2f(-0.2f * log2f(fmaxf(en, 1e-10f)));
            fac = fminf(fmaxf(fac, 0.2f), 10.0f);

            if (accept) { t += dt_c; yv = y5; }
            if (!done) dt = dt_c * fac;
            done = done || (t >= t1 - 1e-8f);
            if (__all(done)) break;
        }

        *(float2*)&out[(size_t)elem * (NSEG * 64) + (seg - 1) * 64 + 2 * sub] = yv;
    }
}

extern "C" void kernel_launch(void* const* d_in, const int* in_sizes, int n_in,
                              void* d_out, int out_size, void* d_ws, size_t ws_size,
                              hipStream_t stream) {
    const float* history = (const float*)d_in[0];
    const float* W1 = (const float*)d_in[1];
    const float* b1 = (const float*)d_in[2];
    const float* W2 = (const float*)d_in[3];
    const float* b2 = (const float*)d_in[4];
    const float* W3 = (const float*)d_in[5];
    const float* b3 = (const float*)d_in[6];
    float* out = (float*)d_out;

    ode_kernel<<<dim3(NB / 8), dim3(256), 0, stream>>>(history, W1, b1, W2, b2, W3, b3, out);
}

// Round 3
// 335.661 us; speedup vs baseline: 4.7643x; 4.7643x over previous
//
#include <hip/hip_runtime.h>
#include <math.h>

#define NB    2048
#define NSEG  20
#define MAXIT 48

typedef __attribute__((ext_vector_type(8))) short bf8_t;
typedef __attribute__((ext_vector_type(4))) float f32x4;

#define cA21 ((float)0.161)
#define cA31 ((float)-0.008480655492356989)
#define cA32 ((float)0.335480655492357)
#define cA41 ((float)2.8971530571054935)
#define cA42 ((float)-6.359448489975075)
#define cA43 ((float)4.3622954328695815)
#define cA51 ((float)5.325864828439257)
#define cA52 ((float)-11.748883564062828)
#define cA53 ((float)7.4955393428898365)
#define cA54 ((float)-0.09249506636175525)
#define cA61 ((float)5.86145544294642)
#define cA62 ((float)-12.92096931784711)
#define cA63 ((float)8.159367898576159)
#define cA64 ((float)-0.071584973281401)
#define cA65 ((float)-0.028269050394068383)
#define cB1  ((float)0.09646076681806523)
#define cB2  ((float)0.01)
#define cB3  ((float)0.4798896504144996)
#define cB4  ((float)1.379008574103742)
#define cB5  ((float)-3.290069515436081)
#define cB6  ((float)2.324710524099774)
#define cE1  ((float)-0.001780011052225777)
#define cE2  ((float)-0.0008164344596567469)
#define cE3  ((float)0.007880878010261995)
#define cE4  ((float)-0.1447110071732629)
#define cE5  ((float)0.5823571654525552)
#define cE6  ((float)-0.45808210592918697)
#define cE7  ((float)0.015151515151515152)

__device__ __forceinline__ void split2(float x, short &hi, short &lo) {
    // x ~= bf16(hi) + bf16(lo), truncation-based (x - hi is exact in fp32)
    unsigned u = __float_as_uint(x);
    hi = (short)(u >> 16);
    float r = x - __uint_as_float(u & 0xFFFF0000u);
    lo = (short)(__float_as_uint(r) >> 16);
}

__device__ __forceinline__ float softplus_f(float x) {
    float t = exp2f(-fabsf(x) * 1.442695040888963f);
    return fmaxf(x, 0.0f) + log2f(1.0f + t) * 0.6931471805599453f;
}

__device__ __forceinline__ unsigned pk(short a, short b) {
    return ((unsigned)(unsigned short)a) | (((unsigned)(unsigned short)b) << 16);
}

// 512 threads = 8 waves; block processes 8 elements in lockstep.
// Weights live in per-lane MFMA A-fragments (bf16 hi/lo) for the whole kernel.
// Acts ping-pong through LDS in MFMA B-fragment layout (bank-padded).
// Frag-layout (16x16x32 bf16): A[m=lane&15][k=32c+8*quad+jj]; B[k][n=lane&15];
// C/D: col=lane&15, row=4*quad+reg  (m89-verified).
__global__ __launch_bounds__(512)
void ode_kernel(const float* __restrict__ history,
                const float* __restrict__ W1, const float* __restrict__ b1,
                const float* __restrict__ W2, const float* __restrict__ b2,
                const float* __restrict__ W3, const float* __restrict__ b3,
                float* __restrict__ out)
{
    // chunk = 4 quads * (16 cols * 8 + 8 pad) = 544 shorts (pad kills bank collapse)
    __shared__ alignas(16) short argH[2 * 544], argL[2 * 544];
    __shared__ alignas(16) short h1H[4 * 544], h1L[4 * 544];
    __shared__ alignas(16) short h2H[4 * 544], h2L[4 * 544];
    __shared__ alignas(16) float kcur[8 * 68];   // [e][d], row-padded
    __shared__ int doneF[8];

    const int tid  = threadIdx.x;
    const int wave = tid >> 6, lane = tid & 63;
    const int quad = lane >> 4, col = lane & 15;
    const int jb   = 16 * wave + 4 * quad;       // this lane's D-row base (j or d)

    // ---- preload weight A-fragments (bf16 hi/lo) ----
    bf8_t A1h[2], A1l[2], A2h[4], A2l[4], A3h[4], A3l[4];
#pragma unroll
    for (int c = 0; c < 2; ++c) {
        const float* p = W1 + (size_t)(16 * wave + col) * 64 + 32 * c + 8 * quad;
        bf8_t h, l;
#pragma unroll
        for (int j = 0; j < 8; ++j) { short hs, ls; split2(p[j], hs, ls); h[j] = hs; l[j] = ls; }
        A1h[c] = h; A1l[c] = l;
    }
#pragma unroll
    for (int c = 0; c < 4; ++c) {
        const float* p = W2 + (size_t)(16 * wave + col) * 128 + 32 * c + 8 * quad;
        bf8_t h, l;
#pragma unroll
        for (int j = 0; j < 8; ++j) { short hs, ls; split2(p[j], hs, ls); h[j] = hs; l[j] = ls; }
        A2h[c] = h; A2l[c] = l;
    }
    f32x4 b3f = {0.f, 0.f, 0.f, 0.f};
    if (wave < 4) {
#pragma unroll
        for (int c = 0; c < 4; ++c) {
            const float* p = W3 + (size_t)(16 * wave + col) * 128 + 32 * c + 8 * quad;
            bf8_t h, l;
#pragma unroll
            for (int j = 0; j < 8; ++j) { short hs, ls; split2(p[j], hs, ls); h[j] = hs; l[j] = ls; }
            A3h[c] = h; A3l[c] = l;
        }
        b3f = *(const f32x4*)(b3 + jb);
    } else {
        bf8_t z = {0, 0, 0, 0, 0, 0, 0, 0};
#pragma unroll
        for (int c = 0; c < 4; ++c) { A3h[c] = z; A3l[c] = z; }
    }
    const f32x4 b1f = *(const f32x4*)(b1 + jb);
    const f32x4 b2f = *(const f32x4*)(b2 + jb);

    // phase-A / E mapping: e = wave, d = lane
    const int aidx = (lane >> 5) * 544 + ((lane >> 3) & 3) * 136 + wave * 8 + (lane & 7);
    const int elem = blockIdx.x * 8 + wave;

    auto gemm = [&](const bf8_t* Ah, const bf8_t* Al, const short* BH, const short* BL,
                    int nch) -> f32x4 {
        f32x4 acc = {0.f, 0.f, 0.f, 0.f};
#pragma unroll
        for (int c = 0; c < nch; ++c) {
            const int off = c * 544 + quad * 136 + col * 8;
            bf8_t bh = *(const bf8_t*)(BH + off);
            bf8_t bl = *(const bf8_t*)(BL + off);
            acc = __builtin_amdgcn_mfma_f32_16x16x32_bf16(Al[c], bh, acc, 0, 0, 0);
            acc = __builtin_amdgcn_mfma_f32_16x16x32_bf16(Ah[c], bl, acc, 0, 0, 0);
            acc = __builtin_amdgcn_mfma_f32_16x16x32_bf16(Ah[c], bh, acc, 0, 0, 0);
        }
        return acc;
    };

    auto epi = [&](f32x4 acc, f32x4 bias, short* H, short* L) {
        if (col < 8) {
            const int idx = (jb >> 5) * 544 + ((jb >> 3) & 3) * 136 + col * 8 + (jb & 7);
            short hh[4], ll[4];
#pragma unroll
            for (int r = 0; r < 4; ++r) {
                float v = softplus_f(acc[r] + bias[r]);
                split2(v, hh[r], ll[r]);
            }
            *(uint2*)(H + idx) = make_uint2(pk(hh[0], hh[1]), pk(hh[2], hh[3]));
            *(uint2*)(L + idx) = make_uint2(pk(ll[0], ll[1]), pk(ll[2], ll[3]));
        }
    };

    // one full MLP eval for all 8 elems; args must already be in argH/argL
    auto eval = [&]() {
        __syncthreads();
        f32x4 a1 = gemm(A1h, A1l, argH, argL, 2);
        epi(a1, b1f, h1H, h1L);
        __syncthreads();
        f32x4 a2 = gemm(A2h, A2l, h1H, h1L, 4);
        epi(a2, b2f, h2H, h2L);
        __syncthreads();
        if (wave < 4) {
            f32x4 a3 = gemm(A3h, A3l, h2H, h2L, 4);
            if (col < 8) {
                f32x4 kv;
#pragma unroll
                for (int r = 0; r < 4; ++r) kv[r] = a3[r] + b3f[r];
                *(f32x4*)(kcur + col * 68 + jb) = kv;
            }
        }
        __syncthreads();
    };

    // ---- state (per wave = per element; lane = dim) ----
    float y  = history[((size_t)elem * 15 + 14) * 64 + lane];
    float dt = 0.1f;
    float k1, k2, k3, k4, k5, k6;

    // initial k1 = f(y)  (FSAL thereafter)
    {
        short hi, lo; split2(y, hi, lo);
        argH[aidx] = hi; argL[aidx] = lo;
        eval();
        k1 = kcur[wave * 68 + lane];
    }

#pragma unroll 1
    for (int seg = 1; seg <= NSEG; ++seg) {
        const float t1 = (float)seg;
        float t = t1 - 1.0f;
        bool done = false;

#pragma unroll 1
        for (int it = 0; it < MAXIT; ++it) {
            const float dt_c = fminf(dt, t1 - t);
            const float h = dt_c;
            float y5v = 0.f, k7v = 0.f;

#pragma unroll 1
            for (int st = 2; st <= 7; ++st) {
                float sum;
                switch (st) {
                    case 2: sum = cA21 * k1; break;
                    case 3: sum = fmaf(cA31, k1, cA32 * k2); break;
                    case 4: sum = fmaf(cA41, k1, fmaf(cA42, k2, cA43 * k3)); break;
                    case 5: sum = fmaf(cA51, k1, fmaf(cA52, k2, fmaf(cA53, k3, cA54 * k4))); break;
                    case 6: sum = fmaf(cA61, k1, fmaf(cA62, k2, fmaf(cA63, k3, fmaf(cA64, k4, cA65 * k5)))); break;
                    default: sum = fmaf(cB1, k1, fmaf(cB2, k2, fmaf(cB3, k3, fmaf(cB4, k4, fmaf(cB5, k5, cB6 * k6))))); break;
                }
                float arg = fmaf(h, sum, y);
                if (st == 7) y5v = arg;
                short hi, lo; split2(arg, hi, lo);
                argH[aidx] = hi; argL[aidx] = lo;
                eval();
                float kv = kcur[wave * 68 + lane];
                switch (st) {
                    case 2: k2 = kv; break;
                    case 3: k3 = kv; break;
                    case 4: k4 = kv; break;
                    case 5: k5 = kv; break;
                    case 6: k6 = kv; break;
                    default: k7v = kv; break;
                }
            }

            // error norm (wave = one element, lanes = dims)
            float esum = fmaf(cE1, k1, fmaf(cE2, k2, fmaf(cE3, k3,
                         fmaf(cE4, k4, fmaf(cE5, k5, fmaf(cE6, k6, cE7 * k7v))))));
            float err = h * esum;
            float sc = fmaf(1e-3f, fmaxf(fabsf(y), fabsf(y5v)), 1e-6f);
            float r = err / sc;
            float rr = r * r;
#pragma unroll
            for (int off = 32; off > 0; off >>= 1) rr += __shfl_xor(rr, off, 64);
            float en = sqrtf(rr * (1.0f / 64.0f));

            bool accept = (en <= 1.0f) && !done;
            float fac = 0.9f * exp2f(-0.2f * log2f(fmaxf(en, 1e-10f)));
            fac = fminf(fmaxf(fac, 0.2f), 10.0f);

            if (accept) { t += dt_c; y = y5v; k1 = k7v; }   // FSAL: f(y_new) = k7
            if (!done) dt = dt_c * fac;
            done = done || (t >= t1 - 1e-8f);

            if (lane == 0) doneF[wave] = done ? 1 : 0;
            __syncthreads();
            bool all = true;
#pragma unroll
            for (int e2 = 0; e2 < 8; ++e2) all = all && (doneF[e2] != 0);
            if (all) break;
        }

        out[((size_t)elem * NSEG + (seg - 1)) * 64 + lane] = y;
    }
}

extern "C" void kernel_launch(void* const* d_in, const int* in_sizes, int n_in,
                              void* d_out, int out_size, void* d_ws, size_t ws_size,
                              hipStream_t stream) {
    const float* history = (const float*)d_in[0];
    const float* W1 = (const float*)d_in[1];
    const float* b1 = (const float*)d_in[2];
    const float* W2 = (const float*)d_in[3];
    const float* b2 = (const float*)d_in[4];
    const float* W3 = (const float*)d_in[5];
    const float* b3 = (const float*)d_in[6];
    float* out = (float*)d_out;

    ode_kernel<<<dim3(NB / 8), dim3(512), 0, stream>>>(history, W1, b1, W2, b2, W3, b3, out);
}